// Round 23
// baseline (159.465 us; speedup 1.0000x reference)
//
#include <hip/hip_runtime.h>
#include <stdint.h>

#define EMBED  2048
#define SEQ    2048
#define BATCH  2
#define NHEADS 32
#define NKV    8
#define HDIM   64
#define KVD    512
#define MTOT   (BATCH*SEQ)      // 4096
#define QKVN   (EMBED + 2*KVD)  // 3072

typedef __bf16 bf16x8 __attribute__((ext_vector_type(8)));
typedef float  f32x4  __attribute__((ext_vector_type(4)));
typedef float  f32x8v __attribute__((ext_vector_type(8)));
typedef float  f32x2v __attribute__((ext_vector_type(2)));
typedef float  f32x16 __attribute__((ext_vector_type(16)));

// exp2-domain constants: p = exp(score - 8) = 2^(score*log2e - 8*log2e)
#define QSCALE 0.18033688f     // 0.125 * log2(e)
#define M2     11.541560f      // 8 * log2(e)

static __device__ __forceinline__ unsigned short f2bf(float f) {
    union { float f; unsigned int u; } v; v.f = f;
    return (unsigned short)((v.u + 0x7fffu + ((v.u >> 16) & 1u)) >> 16);
}

static __device__ __forceinline__ void gload_lds16(const void* g, void* l) {
    __builtin_amdgcn_global_load_lds(
        (const __attribute__((address_space(1))) void*)g,
        (__attribute__((address_space(3))) void*)l, 16, 0, 0);
}

template<int N> static __device__ __forceinline__ void waitvm() {
    if constexpr (N == 0) asm volatile("s_waitcnt vmcnt(0)" ::: "memory");
    else if constexpr (N == 2) asm volatile("s_waitcnt vmcnt(2)" ::: "memory");
    else if constexpr (N == 3) asm volatile("s_waitcnt vmcnt(3)" ::: "memory");
    else if constexpr (N == 5) asm volatile("s_waitcnt vmcnt(5)" ::: "memory");
    else asm volatile("s_waitcnt vmcnt(4)" ::: "memory");
}

// ---------------- fused prep: all fp32->bf16 casts + bias pack (1 launch) -----
static __device__ __forceinline__ void cast4(const float* __restrict__ in,
                                             unsigned short* __restrict__ out, int i) {
    float4 f = reinterpret_cast<const float4*>(in)[i];
    ushort4 o;
    o.x = f2bf(f.x); o.y = f2bf(f.y); o.z = f2bf(f.z); o.w = f2bf(f.w);
    reinterpret_cast<ushort4*>(out)[i] = o;
}

__global__ __launch_bounds__(256)
void prep(const float* __restrict__ x,  const float* __restrict__ Wq,
          const float* __restrict__ Wk, const float* __restrict__ Wv,
          const float* __restrict__ Wo, const float* __restrict__ bq,
          const float* __restrict__ bk, const float* __restrict__ bv,
          unsigned short* __restrict__ xb, unsigned short* __restrict__ Wqkvb,
          unsigned short* __restrict__ Wob, float* __restrict__ bqkv)
{
    const int t0 = blockIdx.x * blockDim.x + threadIdx.x;
    const int st = gridDim.x * blockDim.x;
    for (int i = t0; i < (MTOT * EMBED) / 4;  i += st) cast4(x,  xb, i);
    for (int i = t0; i < (EMBED * EMBED) / 4; i += st) cast4(Wq, Wqkvb, i);
    for (int i = t0; i < (KVD * EMBED) / 4;   i += st) cast4(Wk, Wqkvb + EMBED * EMBED, i);
    for (int i = t0; i < (KVD * EMBED) / 4;   i += st) cast4(Wv, Wqkvb + (EMBED + KVD) * EMBED, i);
    for (int i = t0; i < (EMBED * EMBED) / 4; i += st) cast4(Wo, Wob, i);
    if (t0 < QKVN / 4) {
        float4 v = (t0 < EMBED / 4) ? reinterpret_cast<const float4*>(bq)[t0]
                 : (t0 < (EMBED + KVD) / 4) ? reinterpret_cast<const float4*>(bk)[t0 - EMBED / 4]
                 : reinterpret_cast<const float4*>(bv)[t0 - (EMBED + KVD) / 4];
        reinterpret_cast<float4*>(bqkv)[t0] = v;
    }
}

// ---------------- V transpose: QKVb V-slice [t][d] -> VT[b,g][d][t] ----------
__global__ __launch_bounds__(256)
void transpose_v(const unsigned short* __restrict__ qkv,
                 unsigned short* __restrict__ vt)
{
    __shared__ __align__(16) unsigned short T[64][72];   // +8 pad, 144B rows
    const int bg = blockIdx.x & 15;        // b*8+g
    const int bt = blockIdx.x >> 4;        // t-tile 0..31
    const int b  = bg >> 3, g = bg & 7;
    const int tid = threadIdx.x;
    const int tr  = tid >> 2, c = tid & 3;

    const unsigned short* src = qkv + ((size_t)(b * SEQ + bt * 64 + tr)) * QKVN
                              + (EMBED + KVD) + g * HDIM + c * 16;
    uint4 v0 = *reinterpret_cast<const uint4*>(src);
    uint4 v1 = *reinterpret_cast<const uint4*>(src + 8);
    *reinterpret_cast<uint4*>(&T[tr][c * 16])     = v0;
    *reinterpret_cast<uint4*>(&T[tr][c * 16 + 8]) = v1;
    __syncthreads();

    const int dr = tr;
    unsigned short o[16];
#pragma unroll
    for (int j = 0; j < 16; ++j) o[j] = T[c * 16 + j][dr];
    unsigned short* dst = vt + ((size_t)(bg * 64 + dr)) * SEQ + bt * 64 + c * 16;
    *reinterpret_cast<uint4*>(dst)     = *reinterpret_cast<uint4*>(o);
    *reinterpret_cast<uint4*>(dst + 8) = *reinterpret_cast<uint4*>(o + 8);
}

// ================= QKV GEMM: 256x192 tile, reg-prefetch one phase ahead =======
// (round-19/21 version, proven correct)
__global__ __launch_bounds__(512, 1)
void gemm192(const unsigned short* __restrict__ A,
             const unsigned short* __restrict__ B,
             const float* __restrict__ bias,
             unsigned short* __restrict__ C, int M, int N, int K)
{
    constexpr int ASZ   = 256 * 128;         // A tile bytes
    constexpr int BSZ   = 192 * 128;         // B tile bytes
    constexpr int AHALF = ASZ / 2;
    constexpr int BUFSZ = ASZ + BSZ;         // 57344

    __shared__ __align__(16) char lds[2 * BUFSZ];

    const int tid = threadIdx.x;
    const int l   = tid & 63;
    const int w   = tid >> 6;
    const int wr  = w >> 2, wc = w & 3;
    const int lr15 = l & 15;
    const int lkb  = (l >> 4) * 16;

    const int nwg = gridDim.x;
    const int cpx = nwg >> 3;
    const int bid = blockIdx.x;
    const int swz = (bid & 7) * cpx + (bid >> 3);
    const int NMB = M / 256;                 // 16
    const int m0  = (swz % NMB) * 256;
    const int n0  = (swz / NMB) * 192;

    unsigned offA[2][2], dA[2][2];
#pragma unroll
    for (int q = 0; q < 2; ++q)
#pragma unroll
        for (int j = 0; j < 2; ++j) {
            int L  = q * AHALF + (tid + j * 512) * 16;
            int R  = L >> 7;
            int cb = (L & 127) ^ ((R & 7) << 4);
            int lrow = ((R >> 6) & 1) * 128 + (R >> 7) * 64 + (R & 63);
            offA[q][j] = (unsigned)((m0 + lrow) * K * 2 + cb);
            dA[q][j]   = (unsigned)L;
        }
    unsigned offB[3], dB[3];
#pragma unroll
    for (int q = 0; q < 3; ++q) {
        int L  = q * 8192 + tid * 16;
        int R  = L >> 7;
        int cb = (L & 127) ^ ((R & 7) << 4);
        offB[q] = (unsigned)((n0 + R) * K * 2 + cb);
        dB[q]   = (unsigned)(ASZ + L);
    }

#define STAGE_A(q, bw, ku) { _Pragma("unroll") \
    for (int j_ = 0; j_ < 2; ++j_) \
        gload_lds16((const char*)A + offA[q][j_] + (unsigned)(ku) * 128u, (bw) + dA[q][j_]); }
#define STAGE_B(q, bw, ku) \
    gload_lds16((const char*)B + offB[q] + (unsigned)(ku) * 128u, (bw) + dB[q]);

    auto rdA = [&](const char* br, int mi, int kk) -> bf16x8 {
        int row  = (mi >> 2) * 128 + wr * 64 + (mi & 3) * 16 + lr15;
        int byte = (row * 128 + kk * 64 + lkb) ^ ((row & 7) << 4);
        return *reinterpret_cast<const bf16x8*>(br + byte);
    };
    auto rdB = [&](const char* br, int ni, int kk) -> bf16x8 {
        int row  = ni * 64 + wc * 16 + lr15;
        int byte = (row * 128 + kk * 64 + lkb) ^ ((row & 7) << 4);
        return *reinterpret_cast<const bf16x8*>(br + ASZ + byte);
    };

    f32x4 acc[8][3] = {};
    bf16x8 afrLo[4][2], afrHi[4][2], bf[3][2];

    STAGE_A(0, lds, 0); STAGE_B(0, lds, 0); STAGE_B(1, lds, 0);
    STAGE_B(2, lds, 0); STAGE_A(1, lds, 0);
    waitvm<3>();
    __builtin_amdgcn_s_barrier();
#pragma unroll
    for (int mi = 0; mi < 4; ++mi)
#pragma unroll
        for (int kk = 0; kk < 2; ++kk) afrLo[mi][kk] = rdA(lds, mi, kk);
#pragma unroll
    for (int kk = 0; kk < 2; ++kk) bf[0][kk] = rdB(lds, 0, kk);

    const int NKT = K >> 6;
    for (int u = 0; u < NKT; ++u) {
        char* br = lds + (u & 1) * BUFSZ;
        char* bw = lds + ((u & 1) ^ 1) * BUFSZ;
        const bool pf = (u + 1 < NKT);
        const int  ku = u + 1;

        if (pf) STAGE_A(0, bw, ku);
#pragma unroll
        for (int kk = 0; kk < 2; ++kk) bf[1][kk] = rdB(br, 1, kk);
        __builtin_amdgcn_s_setprio(1);
#pragma unroll
        for (int mi = 0; mi < 4; ++mi)
#pragma unroll
            for (int kk = 0; kk < 2; ++kk)
                acc[mi][0] = __builtin_amdgcn_mfma_f32_16x16x32_bf16(afrLo[mi][kk], bf[0][kk], acc[mi][0], 0, 0, 0);
        __builtin_amdgcn_s_setprio(0);
        waitvm<4>();
        __builtin_amdgcn_s_barrier();

        if (pf) STAGE_B(0, bw, ku);
#pragma unroll
        for (int kk = 0; kk < 2; ++kk) bf[2][kk] = rdB(br, 2, kk);
        __builtin_amdgcn_s_setprio(1);
#pragma unroll
        for (int mi = 0; mi < 4; ++mi)
#pragma unroll
            for (int kk = 0; kk < 2; ++kk)
                acc[mi][1] = __builtin_amdgcn_mfma_f32_16x16x32_bf16(afrLo[mi][kk], bf[1][kk], acc[mi][1], 0, 0, 0);
        __builtin_amdgcn_s_setprio(0);
        waitvm<3>();
        __builtin_amdgcn_s_barrier();

        if (pf) STAGE_B(1, bw, ku);
#pragma unroll
        for (int mi = 0; mi < 4; ++mi)
#pragma unroll
            for (int kk = 0; kk < 2; ++kk) afrHi[mi][kk] = rdA(br, 4 + mi, kk);
        __builtin_amdgcn_s_setprio(1);
#pragma unroll
        for (int mi = 0; mi < 4; ++mi)
#pragma unroll
            for (int kk = 0; kk < 2; ++kk)
                acc[mi][2] = __builtin_amdgcn_mfma_f32_16x16x32_bf16(afrLo[mi][kk], bf[2][kk], acc[mi][2], 0, 0, 0);
        __builtin_amdgcn_s_setprio(0);

        if (pf) STAGE_B(2, bw, ku);
        __builtin_amdgcn_s_setprio(1);
#pragma unroll
        for (int mi = 0; mi < 4; ++mi)
#pragma unroll
            for (int kk = 0; kk < 2; ++kk)
                acc[4 + mi][0] = __builtin_amdgcn_mfma_f32_16x16x32_bf16(afrHi[mi][kk], bf[0][kk], acc[4 + mi][0], 0, 0, 0);
        __builtin_amdgcn_s_setprio(0);

        if (pf) STAGE_A(1, bw, ku);
        __builtin_amdgcn_s_setprio(1);
#pragma unroll
        for (int mi = 0; mi < 4; ++mi)
#pragma unroll
            for (int kk = 0; kk < 2; ++kk)
                acc[4 + mi][1] = __builtin_amdgcn_mfma_f32_16x16x32_bf16(afrHi[mi][kk], bf[1][kk], acc[4 + mi][1], 0, 0, 0);
        __builtin_amdgcn_s_setprio(0);

        __builtin_amdgcn_s_setprio(1);
#pragma unroll
        for (int mi = 0; mi < 4; ++mi)
#pragma unroll
            for (int kk = 0; kk < 2; ++kk)
                acc[4 + mi][2] = __builtin_amdgcn_mfma_f32_16x16x32_bf16(afrHi[mi][kk], bf[2][kk], acc[4 + mi][2], 0, 0, 0);
        __builtin_amdgcn_s_setprio(0);
        waitvm<3>();
        __builtin_amdgcn_s_barrier();
        if (pf) {
#pragma unroll
            for (int mi = 0; mi < 4; ++mi)
#pragma unroll
                for (int kk = 0; kk < 2; ++kk) afrLo[mi][kk] = rdA(bw, mi, kk);
#pragma unroll
            for (int kk = 0; kk < 2; ++kk) bf[0][kk] = rdB(bw, 0, kk);
        }
    }
#undef STAGE_A
#undef STAGE_B

    float bv[3];
#pragma unroll
    for (int ni = 0; ni < 3; ++ni) bv[ni] = bias[n0 + ni * 64 + wc * 16 + lr15];
#pragma unroll
    for (int mi = 0; mi < 8; ++mi)
#pragma unroll
        for (int ni = 0; ni < 3; ++ni)
#pragma unroll
            for (int r = 0; r < 4; ++r) {
                int row = m0 + wr * 128 + mi * 16 + (l >> 4) * 4 + r;
                int col = n0 + ni * 64 + wc * 16 + lr15;
                C[(size_t)row * N + col] = f2bf(acc[mi][ni][r] + bv[ni]);
            }
}

// ================= O-proj GEMM: 256x128 tile, gemm192-style reg-prefetch ======
// (round-22 version, proven correct)
__global__ __launch_bounds__(512, 1)
void gemmO(const unsigned short* __restrict__ A,
           const unsigned short* __restrict__ B,
           const float* __restrict__ bias,
           float* __restrict__ C, int M, int N, int K)
{
    constexpr int ASZ   = 256 * 128;         // 32KB
    constexpr int BSZ   = 128 * 128;         // 16KB
    constexpr int AHALF = ASZ / 2;
    constexpr int BUFSZ = ASZ + BSZ;         // 48KB

    __shared__ __align__(16) char lds[2 * BUFSZ];

    const int tid = threadIdx.x;
    const int l   = tid & 63;
    const int w   = tid >> 6;
    const int wr  = w >> 2, wc = w & 3;
    const int lr15 = l & 15;
    const int lkb  = (l >> 4) * 16;

    const int nwg = gridDim.x;
    const int cpx = nwg >> 3;
    const int bid = blockIdx.x;
    const int swz = (bid & 7) * cpx + (bid >> 3);
    const int NMB = M / 256;                 // 16
    const int m0  = (swz % NMB) * 256;
    const int n0  = (swz / NMB) * 128;

    unsigned offA[2][2], dA[2][2];
#pragma unroll
    for (int q = 0; q < 2; ++q)
#pragma unroll
        for (int j = 0; j < 2; ++j) {
            int L  = q * AHALF + (tid + j * 512) * 16;
            int R  = L >> 7;
            int cb = (L & 127) ^ ((R & 7) << 4);
            int lrow = ((R >> 6) & 1) * 128 + (R >> 7) * 64 + (R & 63);
            offA[q][j] = (unsigned)((m0 + lrow) * K * 2 + cb);
            dA[q][j]   = (unsigned)L;
        }
    unsigned offB[2], dB[2];
#pragma unroll
    for (int q = 0; q < 2; ++q) {
        int L  = q * 8192 + tid * 16;
        int R  = L >> 7;                     // LDS row
        int cb = (L & 127) ^ ((R & 7) << 4);
        int r6 = R & 63;
        int lrow = (r6 >> 4) * 32 + q * 16 + (r6 & 15);
        offB[q] = (unsigned)((n0 + lrow) * K * 2 + cb);
        dB[q]   = (unsigned)(ASZ + L);
    }

#define STAGE_A(q, bw, ku) { _Pragma("unroll") \
    for (int j_ = 0; j_ < 2; ++j_) \
        gload_lds16((const char*)A + offA[q][j_] + (unsigned)(ku) * 128u, (bw) + dA[q][j_]); }
#define STAGE_B(q, bw, ku) \
    gload_lds16((const char*)B + offB[q] + (unsigned)(ku) * 128u, (bw) + dB[q]);

    auto rdA = [&](const char* br, int mi, int kk) -> bf16x8 {
        int row  = (mi >> 2) * 128 + wr * 64 + (mi & 3) * 16 + lr15;
        int byte = (row * 128 + kk * 64 + lkb) ^ ((row & 7) << 4);
        return *reinterpret_cast<const bf16x8*>(br + byte);
    };
    auto rdB = [&](const char* br, int ni, int kk) -> bf16x8 {
        int row  = ni * 64 + wc * 16 + lr15;
        int byte = (row * 128 + kk * 64 + lkb) ^ ((row & 7) << 4);
        return *reinterpret_cast<const bf16x8*>(br + ASZ + byte);
    };

    f32x4 acc[8][2] = {};
    bf16x8 afrLo[4][2], afrHi[4][2], bf[2][2];

    STAGE_A(0, lds, 0); STAGE_B(0, lds, 0); STAGE_B(1, lds, 0); STAGE_A(1, lds, 0);
    waitvm<3>();
    __builtin_amdgcn_s_barrier();
#pragma unroll
    for (int mi = 0; mi < 4; ++mi)
#pragma unroll
        for (int kk = 0; kk < 2; ++kk) afrLo[mi][kk] = rdA(lds, mi, kk);
#pragma unroll
    for (int kk = 0; kk < 2; ++kk) bf[0][kk] = rdB(lds, 0, kk);

    const int NKT = K >> 6;
    for (int u = 0; u < NKT; ++u) {
        char* br = lds + (u & 1) * BUFSZ;
        char* bw = lds + ((u & 1) ^ 1) * BUFSZ;
        const bool pf = (u + 1 < NKT);
        const int  ku = u + 1;

        if (pf) STAGE_A(0, bw, ku);
        __builtin_amdgcn_s_setprio(1);
#pragma unroll
        for (int mi = 0; mi < 4; ++mi)
#pragma unroll
            for (int kk = 0; kk < 2; ++kk)
                acc[mi][0] = __builtin_amdgcn_mfma_f32_16x16x32_bf16(afrLo[mi][kk], bf[0][kk], acc[mi][0], 0, 0, 0);
        __builtin_amdgcn_s_setprio(0);
        if (pf) waitvm<4>(); else waitvm<2>();
        __builtin_amdgcn_s_barrier();
#pragma unroll
        for (int kk = 0; kk < 2; ++kk) bf[1][kk] = rdB(br, 1, kk);

        if (pf) STAGE_B(0, bw, ku);
        __builtin_amdgcn_s_setprio(1);
#pragma unroll
        for (int mi = 0; mi < 4; ++mi)
#pragma unroll
            for (int kk = 0; kk < 2; ++kk)
                acc[mi][1] = __builtin_amdgcn_mfma_f32_16x16x32_bf16(afrLo[mi][kk], bf[1][kk], acc[mi][1], 0, 0, 0);
        __builtin_amdgcn_s_setprio(0);
        if (pf) waitvm<3>(); else waitvm<0>();
        __builtin_amdgcn_s_barrier();
#pragma unroll
        for (int mi = 0; mi < 4; ++mi)
#pragma unroll
            for (int kk = 0; kk < 2; ++kk) afrHi[mi][kk] = rdA(br, 4 + mi, kk);

        if (pf) STAGE_B(1, bw, ku);
        __builtin_amdgcn_s_setprio(1);
#pragma unroll
        for (int mi = 0; mi < 4; ++mi)
#pragma unroll
            for (int kk = 0; kk < 2; ++kk)
                acc[4 + mi][0] = __builtin_amdgcn_mfma_f32_16x16x32_bf16(afrHi[mi][kk], bf[0][kk], acc[4 + mi][0], 0, 0, 0);
        __builtin_amdgcn_s_setprio(0);

        if (pf) STAGE_A(1, bw, ku);
        __builtin_amdgcn_s_setprio(1);
#pragma unroll
        for (int mi = 0; mi < 4; ++mi)
#pragma unroll
            for (int kk = 0; kk < 2; ++kk)
                acc[4 + mi][1] = __builtin_amdgcn_mfma_f32_16x16x32_bf16(afrHi[mi][kk], bf[1][kk], acc[4 + mi][1], 0, 0, 0);
        __builtin_amdgcn_s_setprio(0);
        if (pf) {
            waitvm<3>();
            __builtin_amdgcn_s_barrier();
#pragma unroll
            for (int mi = 0; mi < 4; ++mi)
#pragma unroll
                for (int kk = 0; kk < 2; ++kk) afrLo[mi][kk] = rdA(bw, mi, kk);
#pragma unroll
            for (int kk = 0; kk < 2; ++kk) bf[0][kk] = rdB(bw, 0, kk);
        }
    }
#undef STAGE_A
#undef STAGE_B

    float bv[2];
#pragma unroll
    for (int ni = 0; ni < 2; ++ni) bv[ni] = bias[n0 + wc * 32 + ni * 16 + lr15];
#pragma unroll
    for (int mi = 0; mi < 8; ++mi)
#pragma unroll
        for (int ni = 0; ni < 2; ++ni)
#pragma unroll
            for (int r = 0; r < 4; ++r) {
                int row = m0 + wr * 128 + mi * 16 + (l >> 4) * 4 + r;
                int col = n0 + wc * 32 + ni * 16 + lr15;
                C[(size_t)row * N + col] = acc[mi][ni][r] + bv[ni];
            }
}

// ---------------- P-fragment packing: cvt_pk + permlane32_swap (T12) ----------
static __device__ __forceinline__ bf16x8 pack_frag(float p0, float p1, float p2, float p3,
                                                   float p4, float p5, float p6, float p7) {
    unsigned int w0, w1, w2, w3;
    asm("v_cvt_pk_bf16_f32 %0, %1, %2" : "=v"(w0) : "v"(p0), "v"(p1));
    asm("v_cvt_pk_bf16_f32 %0, %1, %2" : "=v"(w1) : "v"(p2), "v"(p3));
    asm("v_cvt_pk_bf16_f32 %0, %1, %2" : "=v"(w2) : "v"(p4), "v"(p5));
    asm("v_cvt_pk_bf16_f32 %0, %1, %2" : "=v"(w3) : "v"(p6), "v"(p7));
    asm("v_permlane32_swap_b32 %0, %1" : "+v"(w0), "+v"(w2));   // D=low pair, S=high pair
    asm("v_permlane32_swap_b32 %0, %1" : "+v"(w1), "+v"(w3));
    union { unsigned int u[4]; bf16x8 v; } uu;
    uu.u[0] = w0; uu.u[1] = w1; uu.u[2] = w2; uu.u[3] = w3;
    return uu.v;
}

// horizontal sum of 32 floats (two f32x16), pk-add friendly halving tree
static __device__ __forceinline__ float hsum32(f32x16 a, f32x16 b) {
    f32x16 t = a + b;
    f32x8v u = __builtin_shufflevector(t, t, 0,1,2,3,4,5,6,7)
             + __builtin_shufflevector(t, t, 8,9,10,11,12,13,14,15);
    f32x4 v4 = __builtin_shufflevector(u, u, 0,1,2,3)
             + __builtin_shufflevector(u, u, 4,5,6,7);
    f32x2v v2 = __builtin_shufflevector(v4, v4, 0,1)
              + __builtin_shufflevector(v4, v4, 2,3);
    return v2[0] + v2[1];
}

// ---------------- fused causal GQA flash attention ----------------------------
// CU-balanced qt permutation (round 21) + K-fragment register prefetch across
// the tile barrier: kfr[8] holds the NEXT tile's K frags, read immediately
// after the barrier that publishes the staging DMAs (syncthreads drains vmcnt)
// -- QK MFMA issues instantly post-barrier instead of waiting on the LDS-read
// burst that all co-resident blocks fire simultaneously.
__global__ __launch_bounds__(256, 2)
void gqa_attn(const unsigned short* __restrict__ qkv,
              const unsigned short* __restrict__ vtg,
              unsigned short* __restrict__ ctx)
{
    __shared__ __align__(16) unsigned short Ks[2][64 * 64];  // [t][d], XOR-swizzled
    __shared__ __align__(16) unsigned short Vs[2][64 * 64];  // [d][t], XOR-swizzled

    const int bid = blockIdx.x;
    const int g   = bid & 7;
    const int bh  = (bid >> 3) & 3;
    const int b   = bh >> 1;
    const int hp  = bh & 1;
    const int idx = bid >> 5;
    const int s   = idx >> 3, i = idx & 7;
    const int qt  = (s == 0) ? 31 - i : (s == 1) ? i : (s == 2) ? 23 - i : 8 + i;
    const int NT  = qt + 1;

    const int tid = threadIdx.x;
    const int l   = tid & 63;
    const int w   = tid >> 6;
    const int hi  = l >> 5;
    const int lq  = l & 31;

    const int h   = g * 4 + hp * 2 + (w >> 1);
    const int q0  = qt * 64 + (w & 1) * 32;
    const size_t rowb = (size_t)b * SEQ;
    const int kbase = EMBED + g * HDIM;

    bf16x8 qf[4];
    {
        const char* qa = (const char*)qkv + ((rowb + q0 + lq) * QKVN + (size_t)h * HDIM) * 2;
#pragma unroll
        for (int ks = 0; ks < 4; ++ks) {
            bf16x8 ta = *reinterpret_cast<const bf16x8*>(qa + (ks * 16 + hi * 8) * 2);
#pragma unroll
            for (int j = 0; j < 8; ++j)
                ta[j] = (__bf16)((float)ta[j] * QSCALE);
            qf[ks] = ta;
        }
    }

    f32x16 acc0 = {}, acc1 = {};
    float l_run = 0.0f;

    const int Lk0 = tid << 4;
    const int Lk1 = (tid + 256) << 4;
    const int Tk0 = Lk0 ^ (((Lk0 >> 7) & 7) << 4);
    const int Tk1 = Lk1 ^ (((Lk1 >> 7) & 7) << 4);
    const int kr0 = Tk0 >> 7, ko0 = Tk0 & 127;
    const int kr1 = Tk1 >> 7, ko1 = Tk1 & 127;

    const char* vtb = (const char*)vtg + (size_t)(b * 8 + g) * HDIM * SEQ * 2;

    // per-lane LDS frag byte offsets (loop-invariant)
    int ka0[4], ka1[4];
#pragma unroll
    for (int ks = 0; ks < 4; ++ks) {
        const int colb = (ks * 16 + hi * 8) * 2;
        ka0[ks] = (lq * 128 + colb) ^ ((lq & 7) << 4);
        int r1 = 32 + lq;
        ka1[ks] = (r1 * 128 + colb) ^ ((r1 & 7) << 4);
    }

#define STAGE_KV(buf, tt) { \
    gload_lds16((const char*)qkv + ((rowb + (tt) + kr0) * QKVN + kbase) * 2 + ko0, (char*)Ks[buf] + Lk0); \
    gload_lds16((const char*)qkv + ((rowb + (tt) + kr1) * QKVN + kbase) * 2 + ko1, (char*)Ks[buf] + Lk1); \
    gload_lds16(vtb + ((size_t)kr0 * SEQ + (tt)) * 2 + ko0, (char*)Vs[buf] + Lk0); \
    gload_lds16(vtb + ((size_t)kr1 * SEQ + (tt)) * 2 + ko1, (char*)Vs[buf] + Lk1); }

#define READ_KFR(buf) { _Pragma("unroll") \
    for (int ks_ = 0; ks_ < 4; ++ks_) { \
        kfr[ks_]     = *reinterpret_cast<const bf16x8*>((const char*)Ks[buf] + ka0[ks_]); \
        kfr[4 + ks_] = *reinterpret_cast<const bf16x8*>((const char*)Ks[buf] + ka1[ks_]); \
    } }

    bf16x8 kfr[8];

    STAGE_KV(0, 0);
    __syncthreads();
    READ_KFR(0);

    for (int kt = 0; kt < NT; ++kt) {
        const int cur = kt & 1;
        const int t0  = kt * 64;
        const bool haveNext = (kt + 1 < NT);
        if (haveNext) STAGE_KV(cur ^ 1, t0 + 64);

        // QK^T on pre-read K frags (no LDS dependency)
        f32x16 s0 = {}, s1 = {};
        __builtin_amdgcn_s_setprio(1);
#pragma unroll
        for (int ks = 0; ks < 4; ++ks) {
            s0 = __builtin_amdgcn_mfma_f32_32x32x16_bf16(kfr[ks],     qf[ks], s0, 0, 0, 0);
            s1 = __builtin_amdgcn_mfma_f32_32x32x16_bf16(kfr[4 + ks], qf[ks], s1, 0, 0, 0);
        }
        __builtin_amdgcn_s_setprio(0);

        if (kt == qt) {
            const int q = q0 + lq;
#pragma unroll
            for (int r = 0; r < 16; ++r) {
                int tg = t0 + (r & 3) + 8 * (r >> 2) + 4 * hi;
                if (tg > q) s0[r] = -1e30f;
                if (tg + 32 > q) s1[r] = -1e30f;
            }
        }

        s0 = s0 - M2;
        s1 = s1 - M2;
#pragma unroll
        for (int r = 0; r < 16; ++r) {
            s0[r] = __builtin_amdgcn_exp2f(s0[r]);
            s1[r] = __builtin_amdgcn_exp2f(s1[r]);
        }

        float rs = hsum32(s0, s1);
        l_run += rs + __shfl_xor(rs, 32);

        bf16x8 pa[4];
        pa[0] = pack_frag(s0[0], s0[1], s0[2], s0[3], s0[4], s0[5], s0[6], s0[7]);
        pa[1] = pack_frag(s0[8], s0[9], s0[10], s0[11], s0[12], s0[13], s0[14], s0[15]);
        pa[2] = pack_frag(s1[0], s1[1], s1[2], s1[3], s1[4], s1[5], s1[6], s1[7]);
        pa[3] = pack_frag(s1[8], s1[9], s1[10], s1[11], s1[12], s1[13], s1[14], s1[15]);

        const char* VsBuf = (const char*)Vs[cur];
        __builtin_amdgcn_s_setprio(1);
#pragma unroll
        for (int ks = 0; ks < 4; ++ks) {
            bf16x8 vf0 = *reinterpret_cast<const bf16x8*>(VsBuf + ka0[ks]);
            acc0 = __builtin_amdgcn_mfma_f32_32x32x16_bf16(pa[ks], vf0, acc0, 0, 0, 0);
            bf16x8 vf1 = *reinterpret_cast<const bf16x8*>(VsBuf + ka1[ks]);
            acc1 = __builtin_amdgcn_mfma_f32_32x32x16_bf16(pa[ks], vf1, acc1, 0, 0, 0);
        }
        __builtin_amdgcn_s_setprio(0);

        if (haveNext) {
            __syncthreads();          // drains DMAs; Ks[cur^1] now valid
            READ_KFR(cur ^ 1);        // prefetch next tile's K frags
        }
    }
#undef STAGE_KV
#undef READ_KFR

#pragma unroll
    for (int r = 0; r < 16; ++r) {
        int qr  = (r & 3) + 8 * (r >> 2) + 4 * hi;
        int col = h * HDIM + lq;
        float lr = __shfl(l_run, qr);
        size_t row = rowb + q0 + qr;
        ctx[row * EMBED + col]      = f2bf(acc0[r] / lr);
        ctx[row * EMBED + col + 32] = f2bf(acc1[r] / lr);
    }
}

// ---------------- launch ----------------
extern "C" void kernel_launch(void* const* d_in, const int* in_sizes, int n_in,
                              void* d_out, int out_size, void* d_ws, size_t ws_size,
                              hipStream_t stream) {
    (void)in_sizes; (void)n_in; (void)out_size; (void)ws_size;
    const float* x  = (const float*)d_in[0];
    const float* Wq = (const float*)d_in[1];
    const float* bq = (const float*)d_in[2];
    const float* Wk = (const float*)d_in[3];
    const float* bk = (const float*)d_in[4];
    const float* Wv = (const float*)d_in[5];
    const float* bv = (const float*)d_in[6];
    const float* Wo = (const float*)d_in[7];
    const float* bo = (const float*)d_in[8];
    float* out = (float*)d_out;

    char* ws = (char*)d_ws;
    unsigned short* xb    = (unsigned short*)(ws);                 // 16,777,216 B
    unsigned short* Wqkvb = (unsigned short*)(ws + 16777216);      // 12,582,912 B
    unsigned short* Wob   = (unsigned short*)(ws + 29360128);      //  8,388,608 B
    float*          bqkv  = (float*)         (ws + 37748736);      //     12,288 B
    unsigned short* QKVb  = (unsigned short*)(ws + 37761024);      // 25,165,824 B
    unsigned short* ctx   = (unsigned short*)(ws + 62926848);      // 16,777,216 B
    unsigned short* VT    = xb;   // aliases xb: x is dead after the QKV GEMM

    // all casts + bias pack in one launch
    prep<<<2048, 256, 0, stream>>>(x, Wq, Wk, Wv, Wo, bq, bk, bv,
                                   xb, Wqkvb, Wob, bqkv);

    // QKV projection: 256x192 tiles, grid 16*16 = 256 (1 block/CU)
    gemm192<<<dim3(256), 512, 0, stream>>>(
        xb, Wqkvb, bqkv, QKVb, MTOT, QKVN, EMBED);

    // V transpose into VT[b,g][d][t] (xb is dead now)
    transpose_v<<<dim3(512), 256, 0, stream>>>(QKVb, VT);

    // attention: 1024 blocks x 256 threads, single q-tile each, CU-balanced qt
    gqa_attn<<<dim3(1024), 256, 0, stream>>>(QKVb, VT, ctx);

    // output projection: 256x128 tiles, grid 16*16 = 256 (fp32 out)
    gemmO<<<dim3(256), 512, 0, stream>>>(
        ctx, Wob, bo, out, MTOT, EMBED, EMBED);
}

// Round 24
// 157.554 us; speedup vs baseline: 1.0121x; 1.0121x over previous
//
#include <hip/hip_runtime.h>
#include <stdint.h>

#define EMBED  2048
#define SEQ    2048
#define BATCH  2
#define NHEADS 32
#define NKV    8
#define HDIM   64
#define KVD    512
#define MTOT   (BATCH*SEQ)      // 4096
#define QKVN   (EMBED + 2*KVD)  // 3072

typedef __bf16 bf16x8 __attribute__((ext_vector_type(8)));
typedef float  f32x4  __attribute__((ext_vector_type(4)));
typedef float  f32x8v __attribute__((ext_vector_type(8)));
typedef float  f32x2v __attribute__((ext_vector_type(2)));
typedef float  f32x16 __attribute__((ext_vector_type(16)));

// exp2-domain constants: p = exp(score - 8) = 2^(score*log2e - 8*log2e)
#define QSCALE 0.18033688f     // 0.125 * log2(e)
#define M2     11.541560f      // 8 * log2(e)

static __device__ __forceinline__ unsigned short f2bf(float f) {
    union { float f; unsigned int u; } v; v.f = f;
    return (unsigned short)((v.u + 0x7fffu + ((v.u >> 16) & 1u)) >> 16);
}

static __device__ __forceinline__ void gload_lds16(const void* g, void* l) {
    __builtin_amdgcn_global_load_lds(
        (const __attribute__((address_space(1))) void*)g,
        (__attribute__((address_space(3))) void*)l, 16, 0, 0);
}

template<int N> static __device__ __forceinline__ void waitvm() {
    if constexpr (N == 0) asm volatile("s_waitcnt vmcnt(0)" ::: "memory");
    else if constexpr (N == 2) asm volatile("s_waitcnt vmcnt(2)" ::: "memory");
    else if constexpr (N == 3) asm volatile("s_waitcnt vmcnt(3)" ::: "memory");
    else if constexpr (N == 5) asm volatile("s_waitcnt vmcnt(5)" ::: "memory");
    else asm volatile("s_waitcnt vmcnt(4)" ::: "memory");
}

// ---------------- fused prep: all fp32->bf16 casts + bias pack (1 launch) -----
static __device__ __forceinline__ void cast4(const float* __restrict__ in,
                                             unsigned short* __restrict__ out, int i) {
    float4 f = reinterpret_cast<const float4*>(in)[i];
    ushort4 o;
    o.x = f2bf(f.x); o.y = f2bf(f.y); o.z = f2bf(f.z); o.w = f2bf(f.w);
    reinterpret_cast<ushort4*>(out)[i] = o;
}

__global__ __launch_bounds__(256)
void prep(const float* __restrict__ x,  const float* __restrict__ Wq,
          const float* __restrict__ Wk, const float* __restrict__ Wv,
          const float* __restrict__ Wo, const float* __restrict__ bq,
          const float* __restrict__ bk, const float* __restrict__ bv,
          unsigned short* __restrict__ xb, unsigned short* __restrict__ Wqkvb,
          unsigned short* __restrict__ Wob, float* __restrict__ bqkv)
{
    const int t0 = blockIdx.x * blockDim.x + threadIdx.x;
    const int st = gridDim.x * blockDim.x;
    for (int i = t0; i < (MTOT * EMBED) / 4;  i += st) cast4(x,  xb, i);
    for (int i = t0; i < (EMBED * EMBED) / 4; i += st) cast4(Wq, Wqkvb, i);
    for (int i = t0; i < (KVD * EMBED) / 4;   i += st) cast4(Wk, Wqkvb + EMBED * EMBED, i);
    for (int i = t0; i < (KVD * EMBED) / 4;   i += st) cast4(Wv, Wqkvb + (EMBED + KVD) * EMBED, i);
    for (int i = t0; i < (EMBED * EMBED) / 4; i += st) cast4(Wo, Wob, i);
    if (t0 < QKVN / 4) {
        float4 v = (t0 < EMBED / 4) ? reinterpret_cast<const float4*>(bq)[t0]
                 : (t0 < (EMBED + KVD) / 4) ? reinterpret_cast<const float4*>(bk)[t0 - EMBED / 4]
                 : reinterpret_cast<const float4*>(bv)[t0 - (EMBED + KVD) / 4];
        reinterpret_cast<float4*>(bqkv)[t0] = v;
    }
}

// ---------------- V transpose: QKVb V-slice [t][d] -> VT[b,g][d][t] ----------
__global__ __launch_bounds__(256)
void transpose_v(const unsigned short* __restrict__ qkv,
                 unsigned short* __restrict__ vt)
{
    __shared__ __align__(16) unsigned short T[64][72];   // +8 pad, 144B rows
    const int bg = blockIdx.x & 15;        // b*8+g
    const int bt = blockIdx.x >> 4;        // t-tile 0..31
    const int b  = bg >> 3, g = bg & 7;
    const int tid = threadIdx.x;
    const int tr  = tid >> 2, c = tid & 3;

    const unsigned short* src = qkv + ((size_t)(b * SEQ + bt * 64 + tr)) * QKVN
                              + (EMBED + KVD) + g * HDIM + c * 16;
    uint4 v0 = *reinterpret_cast<const uint4*>(src);
    uint4 v1 = *reinterpret_cast<const uint4*>(src + 8);
    *reinterpret_cast<uint4*>(&T[tr][c * 16])     = v0;
    *reinterpret_cast<uint4*>(&T[tr][c * 16 + 8]) = v1;
    __syncthreads();

    const int dr = tr;
    unsigned short o[16];
#pragma unroll
    for (int j = 0; j < 16; ++j) o[j] = T[c * 16 + j][dr];
    unsigned short* dst = vt + ((size_t)(bg * 64 + dr)) * SEQ + bt * 64 + c * 16;
    *reinterpret_cast<uint4*>(dst)     = *reinterpret_cast<uint4*>(o);
    *reinterpret_cast<uint4*>(dst + 8) = *reinterpret_cast<uint4*>(o + 8);
}

// ================= QKV GEMM: 256x192 tile, reg-prefetch one phase ahead =======
// (round-19/21 version, proven correct)
__global__ __launch_bounds__(512, 1)
void gemm192(const unsigned short* __restrict__ A,
             const unsigned short* __restrict__ B,
             const float* __restrict__ bias,
             unsigned short* __restrict__ C, int M, int N, int K)
{
    constexpr int ASZ   = 256 * 128;         // A tile bytes
    constexpr int BSZ   = 192 * 128;         // B tile bytes
    constexpr int AHALF = ASZ / 2;
    constexpr int BUFSZ = ASZ + BSZ;         // 57344

    __shared__ __align__(16) char lds[2 * BUFSZ];

    const int tid = threadIdx.x;
    const int l   = tid & 63;
    const int w   = tid >> 6;
    const int wr  = w >> 2, wc = w & 3;
    const int lr15 = l & 15;
    const int lkb  = (l >> 4) * 16;

    const int nwg = gridDim.x;
    const int cpx = nwg >> 3;
    const int bid = blockIdx.x;
    const int swz = (bid & 7) * cpx + (bid >> 3);
    const int NMB = M / 256;                 // 16
    const int m0  = (swz % NMB) * 256;
    const int n0  = (swz / NMB) * 192;

    unsigned offA[2][2], dA[2][2];
#pragma unroll
    for (int q = 0; q < 2; ++q)
#pragma unroll
        for (int j = 0; j < 2; ++j) {
            int L  = q * AHALF + (tid + j * 512) * 16;
            int R  = L >> 7;
            int cb = (L & 127) ^ ((R & 7) << 4);
            int lrow = ((R >> 6) & 1) * 128 + (R >> 7) * 64 + (R & 63);
            offA[q][j] = (unsigned)((m0 + lrow) * K * 2 + cb);
            dA[q][j]   = (unsigned)L;
        }
    unsigned offB[3], dB[3];
#pragma unroll
    for (int q = 0; q < 3; ++q) {
        int L  = q * 8192 + tid * 16;
        int R  = L >> 7;
        int cb = (L & 127) ^ ((R & 7) << 4);
        offB[q] = (unsigned)((n0 + R) * K * 2 + cb);
        dB[q]   = (unsigned)(ASZ + L);
    }

#define STAGE_A(q, bw, ku) { _Pragma("unroll") \
    for (int j_ = 0; j_ < 2; ++j_) \
        gload_lds16((const char*)A + offA[q][j_] + (unsigned)(ku) * 128u, (bw) + dA[q][j_]); }
#define STAGE_B(q, bw, ku) \
    gload_lds16((const char*)B + offB[q] + (unsigned)(ku) * 128u, (bw) + dB[q]);

    auto rdA = [&](const char* br, int mi, int kk) -> bf16x8 {
        int row  = (mi >> 2) * 128 + wr * 64 + (mi & 3) * 16 + lr15;
        int byte = (row * 128 + kk * 64 + lkb) ^ ((row & 7) << 4);
        return *reinterpret_cast<const bf16x8*>(br + byte);
    };
    auto rdB = [&](const char* br, int ni, int kk) -> bf16x8 {
        int row  = ni * 64 + wc * 16 + lr15;
        int byte = (row * 128 + kk * 64 + lkb) ^ ((row & 7) << 4);
        return *reinterpret_cast<const bf16x8*>(br + ASZ + byte);
    };

    f32x4 acc[8][3] = {};
    bf16x8 afrLo[4][2], afrHi[4][2], bf[3][2];

    STAGE_A(0, lds, 0); STAGE_B(0, lds, 0); STAGE_B(1, lds, 0);
    STAGE_B(2, lds, 0); STAGE_A(1, lds, 0);
    waitvm<3>();
    __builtin_amdgcn_s_barrier();
#pragma unroll
    for (int mi = 0; mi < 4; ++mi)
#pragma unroll
        for (int kk = 0; kk < 2; ++kk) afrLo[mi][kk] = rdA(lds, mi, kk);
#pragma unroll
    for (int kk = 0; kk < 2; ++kk) bf[0][kk] = rdB(lds, 0, kk);

    const int NKT = K >> 6;
    for (int u = 0; u < NKT; ++u) {
        char* br = lds + (u & 1) * BUFSZ;
        char* bw = lds + ((u & 1) ^ 1) * BUFSZ;
        const bool pf = (u + 1 < NKT);
        const int  ku = u + 1;

        if (pf) STAGE_A(0, bw, ku);
#pragma unroll
        for (int kk = 0; kk < 2; ++kk) bf[1][kk] = rdB(br, 1, kk);
        __builtin_amdgcn_s_setprio(1);
#pragma unroll
        for (int mi = 0; mi < 4; ++mi)
#pragma unroll
            for (int kk = 0; kk < 2; ++kk)
                acc[mi][0] = __builtin_amdgcn_mfma_f32_16x16x32_bf16(afrLo[mi][kk], bf[0][kk], acc[mi][0], 0, 0, 0);
        __builtin_amdgcn_s_setprio(0);
        waitvm<4>();
        __builtin_amdgcn_s_barrier();

        if (pf) STAGE_B(0, bw, ku);
#pragma unroll
        for (int kk = 0; kk < 2; ++kk) bf[2][kk] = rdB(br, 2, kk);
        __builtin_amdgcn_s_setprio(1);
#pragma unroll
        for (int mi = 0; mi < 4; ++mi)
#pragma unroll
            for (int kk = 0; kk < 2; ++kk)
                acc[mi][1] = __builtin_amdgcn_mfma_f32_16x16x32_bf16(afrLo[mi][kk], bf[1][kk], acc[mi][1], 0, 0, 0);
        __builtin_amdgcn_s_setprio(0);
        waitvm<3>();
        __builtin_amdgcn_s_barrier();

        if (pf) STAGE_B(1, bw, ku);
#pragma unroll
        for (int mi = 0; mi < 4; ++mi)
#pragma unroll
            for (int kk = 0; kk < 2; ++kk) afrHi[mi][kk] = rdA(br, 4 + mi, kk);
        __builtin_amdgcn_s_setprio(1);
#pragma unroll
        for (int mi = 0; mi < 4; ++mi)
#pragma unroll
            for (int kk = 0; kk < 2; ++kk)
                acc[mi][2] = __builtin_amdgcn_mfma_f32_16x16x32_bf16(afrLo[mi][kk], bf[2][kk], acc[mi][2], 0, 0, 0);
        __builtin_amdgcn_s_setprio(0);

        if (pf) STAGE_B(2, bw, ku);
        __builtin_amdgcn_s_setprio(1);
#pragma unroll
        for (int mi = 0; mi < 4; ++mi)
#pragma unroll
            for (int kk = 0; kk < 2; ++kk)
                acc[4 + mi][0] = __builtin_amdgcn_mfma_f32_16x16x32_bf16(afrHi[mi][kk], bf[0][kk], acc[4 + mi][0], 0, 0, 0);
        __builtin_amdgcn_s_setprio(0);

        if (pf) STAGE_A(1, bw, ku);
        __builtin_amdgcn_s_setprio(1);
#pragma unroll
        for (int mi = 0; mi < 4; ++mi)
#pragma unroll
            for (int kk = 0; kk < 2; ++kk)
                acc[4 + mi][1] = __builtin_amdgcn_mfma_f32_16x16x32_bf16(afrHi[mi][kk], bf[1][kk], acc[4 + mi][1], 0, 0, 0);
        __builtin_amdgcn_s_setprio(0);

        __builtin_amdgcn_s_setprio(1);
#pragma unroll
        for (int mi = 0; mi < 4; ++mi)
#pragma unroll
            for (int kk = 0; kk < 2; ++kk)
                acc[4 + mi][2] = __builtin_amdgcn_mfma_f32_16x16x32_bf16(afrHi[mi][kk], bf[2][kk], acc[4 + mi][2], 0, 0, 0);
        __builtin_amdgcn_s_setprio(0);
        waitvm<3>();
        __builtin_amdgcn_s_barrier();
        if (pf) {
#pragma unroll
            for (int mi = 0; mi < 4; ++mi)
#pragma unroll
                for (int kk = 0; kk < 2; ++kk) afrLo[mi][kk] = rdA(bw, mi, kk);
#pragma unroll
            for (int kk = 0; kk < 2; ++kk) bf[0][kk] = rdB(bw, 0, kk);
        }
    }
#undef STAGE_A
#undef STAGE_B

    float bv[3];
#pragma unroll
    for (int ni = 0; ni < 3; ++ni) bv[ni] = bias[n0 + ni * 64 + wc * 16 + lr15];
#pragma unroll
    for (int mi = 0; mi < 8; ++mi)
#pragma unroll
        for (int ni = 0; ni < 3; ++ni)
#pragma unroll
            for (int r = 0; r < 4; ++r) {
                int row = m0 + wr * 128 + mi * 16 + (l >> 4) * 4 + r;
                int col = n0 + ni * 64 + wc * 16 + lr15;
                C[(size_t)row * N + col] = f2bf(acc[mi][ni][r] + bv[ni]);
            }
}

// ================= O-proj GEMM: 256x128 tile, gemm192-style reg-prefetch ======
// (round-22 version, proven correct)
__global__ __launch_bounds__(512, 1)
void gemmO(const unsigned short* __restrict__ A,
           const unsigned short* __restrict__ B,
           const float* __restrict__ bias,
           float* __restrict__ C, int M, int N, int K)
{
    constexpr int ASZ   = 256 * 128;         // 32KB
    constexpr int BSZ   = 128 * 128;         // 16KB
    constexpr int AHALF = ASZ / 2;
    constexpr int BUFSZ = ASZ + BSZ;         // 48KB

    __shared__ __align__(16) char lds[2 * BUFSZ];

    const int tid = threadIdx.x;
    const int l   = tid & 63;
    const int w   = tid >> 6;
    const int wr  = w >> 2, wc = w & 3;
    const int lr15 = l & 15;
    const int lkb  = (l >> 4) * 16;

    const int nwg = gridDim.x;
    const int cpx = nwg >> 3;
    const int bid = blockIdx.x;
    const int swz = (bid & 7) * cpx + (bid >> 3);
    const int NMB = M / 256;                 // 16
    const int m0  = (swz % NMB) * 256;
    const int n0  = (swz / NMB) * 128;

    unsigned offA[2][2], dA[2][2];
#pragma unroll
    for (int q = 0; q < 2; ++q)
#pragma unroll
        for (int j = 0; j < 2; ++j) {
            int L  = q * AHALF + (tid + j * 512) * 16;
            int R  = L >> 7;
            int cb = (L & 127) ^ ((R & 7) << 4);
            int lrow = ((R >> 6) & 1) * 128 + (R >> 7) * 64 + (R & 63);
            offA[q][j] = (unsigned)((m0 + lrow) * K * 2 + cb);
            dA[q][j]   = (unsigned)L;
        }
    unsigned offB[2], dB[2];
#pragma unroll
    for (int q = 0; q < 2; ++q) {
        int L  = q * 8192 + tid * 16;
        int R  = L >> 7;                     // LDS row
        int cb = (L & 127) ^ ((R & 7) << 4);
        int r6 = R & 63;
        int lrow = (r6 >> 4) * 32 + q * 16 + (r6 & 15);
        offB[q] = (unsigned)((n0 + lrow) * K * 2 + cb);
        dB[q]   = (unsigned)(ASZ + L);
    }

#define STAGE_A(q, bw, ku) { _Pragma("unroll") \
    for (int j_ = 0; j_ < 2; ++j_) \
        gload_lds16((const char*)A + offA[q][j_] + (unsigned)(ku) * 128u, (bw) + dA[q][j_]); }
#define STAGE_B(q, bw, ku) \
    gload_lds16((const char*)B + offB[q] + (unsigned)(ku) * 128u, (bw) + dB[q]);

    auto rdA = [&](const char* br, int mi, int kk) -> bf16x8 {
        int row  = (mi >> 2) * 128 + wr * 64 + (mi & 3) * 16 + lr15;
        int byte = (row * 128 + kk * 64 + lkb) ^ ((row & 7) << 4);
        return *reinterpret_cast<const bf16x8*>(br + byte);
    };
    auto rdB = [&](const char* br, int ni, int kk) -> bf16x8 {
        int row  = ni * 64 + wc * 16 + lr15;
        int byte = (row * 128 + kk * 64 + lkb) ^ ((row & 7) << 4);
        return *reinterpret_cast<const bf16x8*>(br + ASZ + byte);
    };

    f32x4 acc[8][2] = {};
    bf16x8 afrLo[4][2], afrHi[4][2], bf[2][2];

    STAGE_A(0, lds, 0); STAGE_B(0, lds, 0); STAGE_B(1, lds, 0); STAGE_A(1, lds, 0);
    waitvm<3>();
    __builtin_amdgcn_s_barrier();
#pragma unroll
    for (int mi = 0; mi < 4; ++mi)
#pragma unroll
        for (int kk = 0; kk < 2; ++kk) afrLo[mi][kk] = rdA(lds, mi, kk);
#pragma unroll
    for (int kk = 0; kk < 2; ++kk) bf[0][kk] = rdB(lds, 0, kk);

    const int NKT = K >> 6;
    for (int u = 0; u < NKT; ++u) {
        char* br = lds + (u & 1) * BUFSZ;
        char* bw = lds + ((u & 1) ^ 1) * BUFSZ;
        const bool pf = (u + 1 < NKT);
        const int  ku = u + 1;

        if (pf) STAGE_A(0, bw, ku);
        __builtin_amdgcn_s_setprio(1);
#pragma unroll
        for (int mi = 0; mi < 4; ++mi)
#pragma unroll
            for (int kk = 0; kk < 2; ++kk)
                acc[mi][0] = __builtin_amdgcn_mfma_f32_16x16x32_bf16(afrLo[mi][kk], bf[0][kk], acc[mi][0], 0, 0, 0);
        __builtin_amdgcn_s_setprio(0);
        if (pf) waitvm<4>(); else waitvm<2>();
        __builtin_amdgcn_s_barrier();
#pragma unroll
        for (int kk = 0; kk < 2; ++kk) bf[1][kk] = rdB(br, 1, kk);

        if (pf) STAGE_B(0, bw, ku);
        __builtin_amdgcn_s_setprio(1);
#pragma unroll
        for (int mi = 0; mi < 4; ++mi)
#pragma unroll
            for (int kk = 0; kk < 2; ++kk)
                acc[mi][1] = __builtin_amdgcn_mfma_f32_16x16x32_bf16(afrLo[mi][kk], bf[1][kk], acc[mi][1], 0, 0, 0);
        __builtin_amdgcn_s_setprio(0);
        if (pf) waitvm<3>(); else waitvm<0>();
        __builtin_amdgcn_s_barrier();
#pragma unroll
        for (int mi = 0; mi < 4; ++mi)
#pragma unroll
            for (int kk = 0; kk < 2; ++kk) afrHi[mi][kk] = rdA(br, 4 + mi, kk);

        if (pf) STAGE_B(1, bw, ku);
        __builtin_amdgcn_s_setprio(1);
#pragma unroll
        for (int mi = 0; mi < 4; ++mi)
#pragma unroll
            for (int kk = 0; kk < 2; ++kk)
                acc[4 + mi][0] = __builtin_amdgcn_mfma_f32_16x16x32_bf16(afrHi[mi][kk], bf[0][kk], acc[4 + mi][0], 0, 0, 0);
        __builtin_amdgcn_s_setprio(0);

        if (pf) STAGE_A(1, bw, ku);
        __builtin_amdgcn_s_setprio(1);
#pragma unroll
        for (int mi = 0; mi < 4; ++mi)
#pragma unroll
            for (int kk = 0; kk < 2; ++kk)
                acc[4 + mi][1] = __builtin_amdgcn_mfma_f32_16x16x32_bf16(afrHi[mi][kk], bf[1][kk], acc[4 + mi][1], 0, 0, 0);
        __builtin_amdgcn_s_setprio(0);
        if (pf) {
            waitvm<3>();
            __builtin_amdgcn_s_barrier();
#pragma unroll
            for (int mi = 0; mi < 4; ++mi)
#pragma unroll
                for (int kk = 0; kk < 2; ++kk) afrLo[mi][kk] = rdA(bw, mi, kk);
#pragma unroll
            for (int kk = 0; kk < 2; ++kk) bf[0][kk] = rdB(bw, 0, kk);
        }
    }
#undef STAGE_A
#undef STAGE_B

    float bv[2];
#pragma unroll
    for (int ni = 0; ni < 2; ++ni) bv[ni] = bias[n0 + wc * 32 + ni * 16 + lr15];
#pragma unroll
    for (int mi = 0; mi < 8; ++mi)
#pragma unroll
        for (int ni = 0; ni < 2; ++ni)
#pragma unroll
            for (int r = 0; r < 4; ++r) {
                int row = m0 + wr * 128 + mi * 16 + (l >> 4) * 4 + r;
                int col = n0 + wc * 32 + ni * 16 + lr15;
                C[(size_t)row * N + col] = acc[mi][ni][r] + bv[ni];
            }
}

// ---------------- P-fragment packing: cvt_pk + permlane32_swap (T12) ----------
static __device__ __forceinline__ bf16x8 pack_frag(float p0, float p1, float p2, float p3,
                                                   float p4, float p5, float p6, float p7) {
    unsigned int w0, w1, w2, w3;
    asm("v_cvt_pk_bf16_f32 %0, %1, %2" : "=v"(w0) : "v"(p0), "v"(p1));
    asm("v_cvt_pk_bf16_f32 %0, %1, %2" : "=v"(w1) : "v"(p2), "v"(p3));
    asm("v_cvt_pk_bf16_f32 %0, %1, %2" : "=v"(w2) : "v"(p4), "v"(p5));
    asm("v_cvt_pk_bf16_f32 %0, %1, %2" : "=v"(w3) : "v"(p6), "v"(p7));
    asm("v_permlane32_swap_b32 %0, %1" : "+v"(w0), "+v"(w2));   // D=low pair, S=high pair
    asm("v_permlane32_swap_b32 %0, %1" : "+v"(w1), "+v"(w3));
    union { unsigned int u[4]; bf16x8 v; } uu;
    uu.u[0] = w0; uu.u[1] = w1; uu.u[2] = w2; uu.u[3] = w3;
    return uu.v;
}

// horizontal sum of 32 floats (two f32x16), pk-add friendly halving tree
static __device__ __forceinline__ float hsum32(f32x16 a, f32x16 b) {
    f32x16 t = a + b;
    f32x8v u = __builtin_shufflevector(t, t, 0,1,2,3,4,5,6,7)
             + __builtin_shufflevector(t, t, 8,9,10,11,12,13,14,15);
    f32x4 v4 = __builtin_shufflevector(u, u, 0,1,2,3)
             + __builtin_shufflevector(u, u, 4,5,6,7);
    f32x2v v2 = __builtin_shufflevector(v4, v4, 0,1)
              + __builtin_shufflevector(v4, v4, 2,3);
    return v2[0] + v2[1];
}

// ---------------- fused causal GQA flash attention ----------------------------
// (round-21/22 best version: CU-balanced qt permutation, no K-frag prefetch --
// the round-23 prefetch cost an occupancy tier at 4 blocks/CU and regressed)
__global__ __launch_bounds__(256, 2)
void gqa_attn(const unsigned short* __restrict__ qkv,
              const unsigned short* __restrict__ vtg,
              unsigned short* __restrict__ ctx)
{
    __shared__ __align__(16) unsigned short Ks[2][64 * 64];  // [t][d], XOR-swizzled
    __shared__ __align__(16) unsigned short Vs[2][64 * 64];  // [d][t], XOR-swizzled

    const int bid = blockIdx.x;
    const int g   = bid & 7;
    const int bh  = (bid >> 3) & 3;
    const int b   = bh >> 1;
    const int hp  = bh & 1;
    const int idx = bid >> 5;
    const int s   = idx >> 3, i = idx & 7;
    const int qt  = (s == 0) ? 31 - i : (s == 1) ? i : (s == 2) ? 23 - i : 8 + i;
    const int NT  = qt + 1;

    const int tid = threadIdx.x;
    const int l   = tid & 63;
    const int w   = tid >> 6;
    const int hi  = l >> 5;
    const int lq  = l & 31;

    const int h   = g * 4 + hp * 2 + (w >> 1);
    const int q0  = qt * 64 + (w & 1) * 32;
    const size_t rowb = (size_t)b * SEQ;
    const int kbase = EMBED + g * HDIM;

    bf16x8 qf[4];
    {
        const char* qa = (const char*)qkv + ((rowb + q0 + lq) * QKVN + (size_t)h * HDIM) * 2;
#pragma unroll
        for (int ks = 0; ks < 4; ++ks) {
            bf16x8 ta = *reinterpret_cast<const bf16x8*>(qa + (ks * 16 + hi * 8) * 2);
#pragma unroll
            for (int j = 0; j < 8; ++j)
                ta[j] = (__bf16)((float)ta[j] * QSCALE);
            qf[ks] = ta;
        }
    }

    f32x16 acc0 = {}, acc1 = {};
    float l_run = 0.0f;

    const int Lk0 = tid << 4;
    const int Lk1 = (tid + 256) << 4;
    const int Tk0 = Lk0 ^ (((Lk0 >> 7) & 7) << 4);
    const int Tk1 = Lk1 ^ (((Lk1 >> 7) & 7) << 4);
    const int kr0 = Tk0 >> 7, ko0 = Tk0 & 127;
    const int kr1 = Tk1 >> 7, ko1 = Tk1 & 127;

    const char* vtb = (const char*)vtg + (size_t)(b * 8 + g) * HDIM * SEQ * 2;

#define STAGE_KV(buf, tt) { \
    gload_lds16((const char*)qkv + ((rowb + (tt) + kr0) * QKVN + kbase) * 2 + ko0, (char*)Ks[buf] + Lk0); \
    gload_lds16((const char*)qkv + ((rowb + (tt) + kr1) * QKVN + kbase) * 2 + ko1, (char*)Ks[buf] + Lk1); \
    gload_lds16(vtb + ((size_t)kr0 * SEQ + (tt)) * 2 + ko0, (char*)Vs[buf] + Lk0); \
    gload_lds16(vtb + ((size_t)kr1 * SEQ + (tt)) * 2 + ko1, (char*)Vs[buf] + Lk1); }

    STAGE_KV(0, 0);
    __syncthreads();

    for (int kt = 0; kt < NT; ++kt) {
        const int cur = kt & 1;
        const int t0  = kt * 64;
        const bool haveNext = (kt + 1 < NT);
        if (haveNext) STAGE_KV(cur ^ 1, t0 + 64);

        const char* KsBuf = (const char*)Ks[cur];
        f32x16 s0 = {}, s1 = {};
        __builtin_amdgcn_s_setprio(1);
#pragma unroll
        for (int ks = 0; ks < 4; ++ks) {
            const int colb = (ks * 16 + hi * 8) * 2;
            int a0 = (lq * 128 + colb) ^ ((lq & 7) << 4);
            bf16x8 kf0 = *reinterpret_cast<const bf16x8*>(KsBuf + a0);
            s0 = __builtin_amdgcn_mfma_f32_32x32x16_bf16(kf0, qf[ks], s0, 0, 0, 0);
            int r1 = 32 + lq;
            int a1 = (r1 * 128 + colb) ^ ((r1 & 7) << 4);
            bf16x8 kf1 = *reinterpret_cast<const bf16x8*>(KsBuf + a1);
            s1 = __builtin_amdgcn_mfma_f32_32x32x16_bf16(kf1, qf[ks], s1, 0, 0, 0);
        }
        __builtin_amdgcn_s_setprio(0);

        if (kt == qt) {
            const int q = q0 + lq;
#pragma unroll
            for (int r = 0; r < 16; ++r) {
                int tg = t0 + (r & 3) + 8 * (r >> 2) + 4 * hi;
                if (tg > q) s0[r] = -1e30f;
                if (tg + 32 > q) s1[r] = -1e30f;
            }
        }

        s0 = s0 - M2;
        s1 = s1 - M2;
#pragma unroll
        for (int r = 0; r < 16; ++r) {
            s0[r] = __builtin_amdgcn_exp2f(s0[r]);
            s1[r] = __builtin_amdgcn_exp2f(s1[r]);
        }

        float rs = hsum32(s0, s1);
        l_run += rs + __shfl_xor(rs, 32);

        bf16x8 pa[4];
        pa[0] = pack_frag(s0[0], s0[1], s0[2], s0[3], s0[4], s0[5], s0[6], s0[7]);
        pa[1] = pack_frag(s0[8], s0[9], s0[10], s0[11], s0[12], s0[13], s0[14], s0[15]);
        pa[2] = pack_frag(s1[0], s1[1], s1[2], s1[3], s1[4], s1[5], s1[6], s1[7]);
        pa[3] = pack_frag(s1[8], s1[9], s1[10], s1[11], s1[12], s1[13], s1[14], s1[15]);

        const char* VsBuf = (const char*)Vs[cur];
        __builtin_amdgcn_s_setprio(1);
#pragma unroll
        for (int ks = 0; ks < 4; ++ks) {
            const int colb = (ks * 16 + hi * 8) * 2;
            int a0 = (lq * 128 + colb) ^ ((lq & 7) << 4);
            bf16x8 vf0 = *reinterpret_cast<const bf16x8*>(VsBuf + a0);
            acc0 = __builtin_amdgcn_mfma_f32_32x32x16_bf16(pa[ks], vf0, acc0, 0, 0, 0);
            int d1 = 32 + lq;
            int a1 = (d1 * 128 + colb) ^ ((d1 & 7) << 4);
            bf16x8 vf1 = *reinterpret_cast<const bf16x8*>(VsBuf + a1);
            acc1 = __builtin_amdgcn_mfma_f32_32x32x16_bf16(pa[ks], vf1, acc1, 0, 0, 0);
        }
        __builtin_amdgcn_s_setprio(0);

        if (haveNext) __syncthreads();
    }
#undef STAGE_KV

#pragma unroll
    for (int r = 0; r < 16; ++r) {
        int qr  = (r & 3) + 8 * (r >> 2) + 4 * hi;
        int col = h * HDIM + lq;
        float lr = __shfl(l_run, qr);
        size_t row = rowb + q0 + qr;
        ctx[row * EMBED + col]      = f2bf(acc0[r] / lr);
        ctx[row * EMBED + col + 32] = f2bf(acc1[r] / lr);
    }
}

// ---------------- launch ----------------
extern "C" void kernel_launch(void* const* d_in, const int* in_sizes, int n_in,
                              void* d_out, int out_size, void* d_ws, size_t ws_size,
                              hipStream_t stream) {
    (void)in_sizes; (void)n_in; (void)out_size; (void)ws_size;
    const float* x  = (const float*)d_in[0];
    const float* Wq = (const float*)d_in[1];
    const float* bq = (const float*)d_in[2];
    const float* Wk = (const float*)d_in[3];
    const float* bk = (const float*)d_in[4];
    const float* Wv = (const float*)d_in[5];
    const float* bv = (const float*)d_in[6];
    const float* Wo = (const float*)d_in[7];
    const float* bo = (const float*)d_in[8];
    float* out = (float*)d_out;

    char* ws = (char*)d_ws;
    unsigned short* xb    = (unsigned short*)(ws);                 // 16,777,216 B
    unsigned short* Wqkvb = (unsigned short*)(ws + 16777216);      // 12,582,912 B
    unsigned short* Wob   = (unsigned short*)(ws + 29360128);      //  8,388,608 B
    float*          bqkv  = (float*)         (ws + 37748736);      //     12,288 B
    unsigned short* QKVb  = (unsigned short*)(ws + 37761024);      // 25,165,824 B
    unsigned short* ctx   = (unsigned short*)(ws + 62926848);      // 16,777,216 B
    unsigned short* VT    = xb;   // aliases xb: x is dead after the QKV GEMM

    // all casts + bias pack in one launch
    prep<<<2048, 256, 0, stream>>>(x, Wq, Wk, Wv, Wo, bq, bk, bv,
                                   xb, Wqkvb, Wob, bqkv);

    // QKV projection: 256x192 tiles, grid 16*16 = 256 (1 block/CU)
    gemm192<<<dim3(256), 512, 0, stream>>>(
        xb, Wqkvb, bqkv, QKVb, MTOT, QKVN, EMBED);

    // V transpose into VT[b,g][d][t] (xb is dead now)
    transpose_v<<<dim3(512), 256, 0, stream>>>(QKVb, VT);

    // attention: 1024 blocks x 256 threads, single q-tile each, CU-balanced qt
    gqa_attn<<<dim3(1024), 256, 0, stream>>>(QKVb, VT, ctx);

    // output projection: 256x128 tiles, grid 16*16 = 256 (fp32 out)
    gemmO<<<dim3(256), 512, 0, stream>>>(
        ctx, Wob, bo, out, MTOT, EMBED, EMBED);
}